// Round 4
// baseline (241.513 us; speedup 1.0000x reference)
//
#include <hip/hip_runtime.h>
#include <stdint.h>

#define SAMPLES   524288
#define BATCH     16
#define T_FRAMES  2048
#define K_FFT     1024
#define HOPSZ     256
#define CACHEPAD  1023
#define NCH       513                  // output freq bins
#define NCH_PAD   576                  // 9 * 64
#define XROW      525312               // 1023 zero-pad + 524288 samples + 1 spare (rows 16B-aligned)
#define XCHUNKS   (XROW / 8)           // 65664 aligned 8-elem output chunks per row
#define XBLOCKS   (257 * BATCH)        // 4112 blocks for the x part
#define WBLOCKS   576                  // 2*576*128 threads / 256

typedef __bf16          bf16x8 __attribute__((ext_vector_type(8)));
typedef float           f32x4  __attribute__((ext_vector_type(4)));
typedef unsigned short  u16x8  __attribute__((ext_vector_type(8)));

__device__ __forceinline__ unsigned short f2bf(float f) {
    union { float f; unsigned u; } v; v.f = f;
    unsigned r = v.u + 0x7fffu + ((v.u >> 16) & 1u);   // round-to-nearest-even
    return (unsigned short)(r >> 16);
}

// ---------- fused prep: x fp32 -> padded bf16 rows, weight fp32 -> bf16 ----
// x part: thread owns ALIGNED output chunk [8j, 8j+8) of Xb row (u16x8 store);
// input samples 8j-1023..8j-1016 gathered via 3 aligned float4 loads.
__global__ void prep(const float* __restrict__ x, const float* __restrict__ w,
                     unsigned short* __restrict__ Xb, unsigned short* __restrict__ Wb) {
    int bid = blockIdx.x;
    if (bid < XBLOCKS) {
        int bat = bid / 257;
        int blk = bid % 257;
        int j = blk * 256 + threadIdx.x;         // chunk index in row
        if (j >= XCHUNKS) return;
        const float* xb = x + (long long)bat * SAMPLES;
        unsigned short* xbo = Xb + (long long)bat * XROW;
        int o0 = j * 8;
        u16x8 v;
        if (j >= 128 && j <= 65537) {            // interior: all loads in-bounds
            const float* p = xb + (o0 - 1024);   // 16B aligned
            f32x4 A  = *(const f32x4*)p;
            f32x4 Bv = *(const f32x4*)(p + 4);
            f32x4 C  = *(const f32x4*)(p + 8);
            v[0] = f2bf(A[1]);  v[1] = f2bf(A[2]);  v[2] = f2bf(A[3]);
            v[3] = f2bf(Bv[0]); v[4] = f2bf(Bv[1]); v[5] = f2bf(Bv[2]);
            v[6] = f2bf(Bv[3]); v[7] = f2bf(C[0]);
        } else {                                  // boundary: predicated scalar
            #pragma unroll
            for (int e = 0; e < 8; ++e) {
                int s = o0 + e - CACHEPAD;
                v[e] = (s >= 0 && s < SAMPLES) ? f2bf(xb[s]) : (unsigned short)0;
            }
        }
        *(u16x8*)&xbo[o0] = v;
    } else {
        int i = (bid - XBLOCKS) * 256 + threadIdx.x;   // 2*576*128 total
        int k0 = (i & 127) * 8;
        int c  = (i >> 7) % NCH_PAD;
        int s  = i / (NCH_PAD * 128);
        if (s >= 2) return;
        u16x8 v;
        if (c < NCH) {
            const float* p = w + ((long long)(s * NCH + c)) * K_FFT + k0;
            f32x4 A  = *(const f32x4*)p;
            f32x4 Bv = *(const f32x4*)(p + 4);
            #pragma unroll
            for (int e = 0; e < 4; ++e) { v[e] = f2bf(A[e]); v[4 + e] = f2bf(Bv[e]); }
        } else {
            #pragma unroll
            for (int e = 0; e < 8; ++e) v[e] = 0;
        }
        *(u16x8*)&Wb[((long long)(s * NCH_PAD + c)) * K_FFT + k0] = v;
    }
}

// ---------- async global -> LDS (16 B per lane, dst = base + lane*16) -----
__device__ __forceinline__ void gll16(const unsigned short* g, unsigned short* s) {
    __builtin_amdgcn_global_load_lds(
        (const __attribute__((address_space(1))) void*)g,
        (__attribute__((address_space(3))) void*)s,
        16, 0, 0);
}

// ---------- main GEMM + magnitude epilogue --------------------------------
// Block tile: 128 channel-rows (cos/sin interleaved per 16) x 128 frames,
// BK = 64. Weights staged in LDS (XOR-swizzled, 8x reuse); FRAME fragments
// loaded DIRECTLY from global to registers (a B-frag is 8 contiguous k of
// one frame = one aligned u16x8 in Xb; 16 rows x 64B fully-coalesced
// segments, L2-resident via the XCD swizzle). Removes the Fs LDS round-trip:
// LDS pipe/CU drops below MFMA pipe -> MFMA-bound structure.
__global__ __launch_bounds__(256, 3)
void stft_gemm(const unsigned short* __restrict__ Xb,
               const unsigned short* __restrict__ Wb,
               float* __restrict__ out) {
    __shared__ unsigned short Ws[128 * 64];   // 16 KB

    const int id  = blockIdx.x;
    const int xcd = id & 7;
    const int idx = id >> 3;        // 0..287
    const int nt  = idx >> 5;       // 0..8  channel tile
    const int ft  = (xcd << 5) | (idx & 31);   // frame tile, striped per XCD

    const int tid = threadIdx.x;
    const int l   = tid & 63;
    const int w   = tid >> 6;
    const int ln  = l & 15;
    const int qd  = l >> 4;

    const int b  = ft >> 4;
    const int t0 = (ft & 15) * 128;            // frame tile never crosses a batch

    const unsigned short* xbase = Xb + (long long)b * XROW;

    // ---- Ws staging: wave w stages rows [w*32, w*32+32), 4 gll16 calls;
    //      call c: row = w*32 + c*8 + (l>>3), global chunk = (l&7)^(row&7).
    const int srow   = l >> 3;
    const int schunk = l & 7;
    const unsigned short* wsrc[4];
    unsigned short* wdst[4];
    #pragma unroll
    for (int c = 0; c < 4; ++c) {
        int r = w * 32 + c * 8 + srow;
        int gchunk = schunk ^ (r & 7);
        int sel = (r >> 4) & 1;
        int chl = ((r >> 5) << 4) | (r & 15);
        int ch  = nt * 64 + chl;                           // < 576, pad rows = 0
        wsrc[c] = Wb + ((long long)(sel * NCH_PAD + ch)) * K_FFT + gchunk * 8;
        wdst[c] = Ws + (w * 32 + c * 8) * 64;
    }

    const int wave_m = w & 1;
    const int wave_n = w >> 1;

    // ---- B (frame) fragment base pointers: frag = 8 contiguous k of frame
    const unsigned short* bbase[4];
    #pragma unroll
    for (int j = 0; j < 4; ++j)
        bbase[j] = xbase + (long long)(t0 + wave_n * 64 + j * 16 + ln) * HOPSZ + qd * 8;

    f32x4 acc[4][4];
    #pragma unroll
    for (int i = 0; i < 4; ++i)
        #pragma unroll
        for (int j = 0; j < 4; ++j)
            acc[i][j] = (f32x4){0.f, 0.f, 0.f, 0.f};

    // A ds_read offsets: row = wave_m*64 + i*16 + ln; lds chunk = (k2*4+qd)^(ln&7)
    int a_off[4][2];
    #pragma unroll
    for (int i = 0; i < 4; ++i)
        #pragma unroll
        for (int k2 = 0; k2 < 2; ++k2) {
            int ck = ((k2 * 4 + qd) ^ (ln & 7)) * 8;
            a_off[i][k2] = (wave_m * 64 + i * 16 + ln) * 64 + ck;
        }

    for (int kk = 0; kk < K_FFT; kk += 64) {
        #pragma unroll
        for (int c = 0; c < 4; ++c) gll16(wsrc[c] + kk, wdst[c]);

        bf16x8 bv[2][4];
        #pragma unroll
        for (int k2 = 0; k2 < 2; ++k2)
            #pragma unroll
            for (int j = 0; j < 4; ++j)
                bv[k2][j] = *(const bf16x8*)(bbase[j] + kk + k2 * 32);

        __syncthreads();

        #pragma unroll
        for (int k2 = 0; k2 < 2; ++k2) {
            bf16x8 av[4];
            #pragma unroll
            for (int i = 0; i < 4; ++i) av[i] = *(const bf16x8*)&Ws[a_off[i][k2]];
            #pragma unroll
            for (int i = 0; i < 4; ++i)
                #pragma unroll
                for (int j = 0; j < 4; ++j)
                    acc[i][j] = __builtin_amdgcn_mfma_f32_16x16x32_bf16(av[i], bv[k2][j], acc[i][j], 0, 0, 0);
        }
        __syncthreads();
    }

    // ---- epilogue: mag = sqrt(max(re^2+im^2, 1e-12)), coalesced stores ----
    // D layout (16x16x32): frame = lane&15, channel-sub = qd*4 + reg.
    #pragma unroll
    for (int p = 0; p < 2; ++p) {
        #pragma unroll
        for (int j = 0; j < 4; ++j) {
            #pragma unroll
            for (int r = 0; r < 4; ++r) {
                float re  = acc[2 * p][j][r];
                float im  = acc[2 * p + 1][j][r];
                float mag = sqrtf(fmaxf(re * re + im * im, 1e-12f));
                int ch = nt * 64 + (wave_m * 2 + p) * 16 + qd * 4 + r;
                int t  = t0 + wave_n * 64 + j * 16 + ln;
                if (ch < NCH)
                    out[((long long)b * NCH + ch) * T_FRAMES + t] = mag;
            }
        }
    }
}

extern "C" void kernel_launch(void* const* d_in, const int* in_sizes, int n_in,
                              void* d_out, int out_size, void* d_ws, size_t ws_size,
                              hipStream_t stream) {
    const float* x  = (const float*)d_in[0];
    const float* wt = (const float*)d_in[1];
    float* out = (float*)d_out;

    unsigned short* Xb = (unsigned short*)d_ws;                              // 16.04 MiB
    unsigned short* Wb = (unsigned short*)((char*)d_ws + (size_t)33554432);  // 2.25 MiB

    prep<<<XBLOCKS + WBLOCKS, 256, 0, stream>>>(x, wt, Xb, Wb);
    stft_gemm<<<dim3(2304), 256, 0, stream>>>(Xb, Wb, out);
}

// Round 5
// 212.666 us; speedup vs baseline: 1.1356x; 1.1356x over previous
//
#include <hip/hip_runtime.h>
#include <stdint.h>

#define SAMPLES   524288
#define BATCH     16
#define T_FRAMES  2048
#define K_FFT     1024
#define HOPSZ     256
#define CACHEPAD  1023
#define NCH       513                  // output freq bins
#define NCH_PAD   576                  // 9 * 64
#define XROW      525312               // 1023 zero-pad + 524288 samples + 1 spare (rows 16B-aligned)
#define XCHUNKS   (XROW / 8)           // 65664 aligned 8-elem output chunks per row
#define XBLOCKS   (257 * BATCH)        // 4112 blocks for the x part
#define WBLOCKS   576                  // 2*576*128 threads / 256

typedef __bf16          bf16x8 __attribute__((ext_vector_type(8)));
typedef float           f32x4  __attribute__((ext_vector_type(4)));
typedef unsigned short  u16x8  __attribute__((ext_vector_type(8)));

__device__ __forceinline__ unsigned short f2bf(float f) {
    union { float f; unsigned u; } v; v.f = f;
    unsigned r = v.u + 0x7fffu + ((v.u >> 16) & 1u);   // round-to-nearest-even
    return (unsigned short)(r >> 16);
}

// ---------- fused prep: x fp32 -> padded bf16 rows, weight fp32 -> bf16 ----
// x part: thread owns ALIGNED output chunk [8j, 8j+8) of Xb row (u16x8 store);
// input samples 8j-1023..8j-1016 gathered via 3 aligned float4 loads.
__global__ void prep(const float* __restrict__ x, const float* __restrict__ w,
                     unsigned short* __restrict__ Xb, unsigned short* __restrict__ Wb) {
    int bid = blockIdx.x;
    if (bid < XBLOCKS) {
        int bat = bid / 257;
        int blk = bid % 257;
        int j = blk * 256 + threadIdx.x;         // chunk index in row
        if (j >= XCHUNKS) return;
        const float* xb = x + (long long)bat * SAMPLES;
        unsigned short* xbo = Xb + (long long)bat * XROW;
        int o0 = j * 8;
        u16x8 v;
        if (j >= 128 && j <= 65537) {            // interior: all loads in-bounds
            const float* p = xb + (o0 - 1024);   // 16B aligned
            f32x4 A  = *(const f32x4*)p;
            f32x4 Bv = *(const f32x4*)(p + 4);
            f32x4 C  = *(const f32x4*)(p + 8);
            v[0] = f2bf(A[1]);  v[1] = f2bf(A[2]);  v[2] = f2bf(A[3]);
            v[3] = f2bf(Bv[0]); v[4] = f2bf(Bv[1]); v[5] = f2bf(Bv[2]);
            v[6] = f2bf(Bv[3]); v[7] = f2bf(C[0]);
        } else {                                  // boundary: predicated scalar
            #pragma unroll
            for (int e = 0; e < 8; ++e) {
                int s = o0 + e - CACHEPAD;
                v[e] = (s >= 0 && s < SAMPLES) ? f2bf(xb[s]) : (unsigned short)0;
            }
        }
        *(u16x8*)&xbo[o0] = v;
    } else {
        int i = (bid - XBLOCKS) * 256 + threadIdx.x;   // 2*576*128 total
        int k0 = (i & 127) * 8;
        int c  = (i >> 7) % NCH_PAD;
        int s  = i / (NCH_PAD * 128);
        if (s >= 2) return;
        u16x8 v;
        if (c < NCH) {
            const float* p = w + ((long long)(s * NCH + c)) * K_FFT + k0;
            f32x4 A  = *(const f32x4*)p;
            f32x4 Bv = *(const f32x4*)(p + 4);
            #pragma unroll
            for (int e = 0; e < 4; ++e) { v[e] = f2bf(A[e]); v[4 + e] = f2bf(Bv[e]); }
        } else {
            #pragma unroll
            for (int e = 0; e < 8; ++e) v[e] = 0;
        }
        *(u16x8*)&Wb[((long long)(s * NCH_PAD + c)) * K_FFT + k0] = v;
    }
}

// ---------- async global -> LDS (16 B per lane, dst = base + lane*16) -----
__device__ __forceinline__ void gll16(const unsigned short* g, unsigned short* s) {
    __builtin_amdgcn_global_load_lds(
        (const __attribute__((address_space(1))) void*)g,
        (__attribute__((address_space(3))) void*)s,
        16, 0, 0);
}

// ---------- main GEMM + magnitude epilogue --------------------------------
// R3 structure (known-good 79 us): 128 ch-rows x 128 frames, BK = 64, both
// operands staged via global_load_lds into XOR-swizzled LDS; XCD-aware block
// swizzle keeps each XCD's staging inside its own L2 (x stripe ~2 MB + Wb
// 2.25 MB). R4's direct-global B-fragments regressed 2x (in-loop vmcnt
// latency) — do not repeat.
__global__ __launch_bounds__(256, 4)
void stft_gemm(const unsigned short* __restrict__ Xb,
               const unsigned short* __restrict__ Wb,
               float* __restrict__ out) {
    __shared__ unsigned short Ws[128 * 64];   // 16 KB
    __shared__ unsigned short Fs[128 * 64];   // 16 KB

    const int id  = blockIdx.x;
    const int xcd = id & 7;
    const int idx = id >> 3;        // 0..287
    const int nt  = idx >> 5;       // 0..8  channel tile (32 consecutive blocks share it)
    const int ft  = (xcd << 5) | (idx & 31);   // 0..255 frame tile, striped per XCD

    const int tid = threadIdx.x;
    const int l   = tid & 63;
    const int w   = tid >> 6;
    const int ln  = l & 15;
    const int qd  = l >> 4;

    const int b  = ft >> 4;
    const int t0 = (ft & 15) * 128;            // frame tile never crosses a batch

    const unsigned short* xbase = Xb + (long long)b * XROW;

    // ---- staging: wave w stages rows [w*32, w*32+32) of Fs and Ws,
    //      4 gll16 calls each; call c: row = w*32 + c*8 + (l>>3),
    //      lds chunk = l&7 (implicit dst), global chunk = (l&7) ^ (row&7).
    const int srow   = l >> 3;
    const int schunk = l & 7;

    const unsigned short* fsrc[4];
    const unsigned short* wsrc[4];
    unsigned short* fdst[4];
    unsigned short* wdst[4];
    #pragma unroll
    for (int c = 0; c < 4; ++c) {
        int r = w * 32 + c * 8 + srow;
        int gchunk = schunk ^ (r & 7);
        fsrc[c] = xbase + (t0 + r) * HOPSZ + gchunk * 8;   // frame r, k-chunk
        int sel = (r >> 4) & 1;
        int chl = ((r >> 5) << 4) | (r & 15);
        int ch  = nt * 64 + chl;                           // < 576, pad rows = 0
        wsrc[c] = Wb + ((long long)(sel * NCH_PAD + ch)) * K_FFT + gchunk * 8;
        fdst[c] = Fs + (w * 32 + c * 8) * 64;
        wdst[c] = Ws + (w * 32 + c * 8) * 64;
    }

    const int wave_m = w & 1;
    const int wave_n = w >> 1;

    f32x4 acc[4][4];
    #pragma unroll
    for (int i = 0; i < 4; ++i)
        #pragma unroll
        for (int j = 0; j < 4; ++j)
            acc[i][j] = (f32x4){0.f, 0.f, 0.f, 0.f};

    // ds_read offsets: row = base + i*16 + ln (row&7 == ln&7);
    // global chunk wanted = k2*4 + qd -> lds chunk = (k2*4+qd) ^ (ln&7)
    int a_off[4][2], b_off[4][2];
    #pragma unroll
    for (int i = 0; i < 4; ++i)
        #pragma unroll
        for (int k2 = 0; k2 < 2; ++k2) {
            int ck = ((k2 * 4 + qd) ^ (ln & 7)) * 8;
            a_off[i][k2] = (wave_m * 64 + i * 16 + ln) * 64 + ck;
            b_off[i][k2] = (wave_n * 64 + i * 16 + ln) * 64 + ck;
        }

    for (int kk = 0; kk < K_FFT; kk += 64) {
        #pragma unroll
        for (int c = 0; c < 4; ++c) gll16(fsrc[c] + kk, fdst[c]);
        #pragma unroll
        for (int c = 0; c < 4; ++c) gll16(wsrc[c] + kk, wdst[c]);
        __syncthreads();

        #pragma unroll
        for (int k2 = 0; k2 < 2; ++k2) {
            bf16x8 av[4], bv[4];
            #pragma unroll
            for (int i = 0; i < 4; ++i) av[i] = *(const bf16x8*)&Ws[a_off[i][k2]];
            #pragma unroll
            for (int j = 0; j < 4; ++j) bv[j] = *(const bf16x8*)&Fs[b_off[j][k2]];
            #pragma unroll
            for (int i = 0; i < 4; ++i)
                #pragma unroll
                for (int j = 0; j < 4; ++j)
                    acc[i][j] = __builtin_amdgcn_mfma_f32_16x16x32_bf16(av[i], bv[j], acc[i][j], 0, 0, 0);
        }
        __syncthreads();
    }

    // ---- epilogue: mag = sqrt(max(re^2+im^2, 1e-12)), coalesced stores ----
    // D layout (16x16x32): frame = lane&15, channel-sub = qd*4 + reg.
    #pragma unroll
    for (int p = 0; p < 2; ++p) {
        #pragma unroll
        for (int j = 0; j < 4; ++j) {
            #pragma unroll
            for (int r = 0; r < 4; ++r) {
                float re  = acc[2 * p][j][r];
                float im  = acc[2 * p + 1][j][r];
                float mag = sqrtf(fmaxf(re * re + im * im, 1e-12f));
                int ch = nt * 64 + (wave_m * 2 + p) * 16 + qd * 4 + r;
                int t  = t0 + wave_n * 64 + j * 16 + ln;
                if (ch < NCH)
                    out[((long long)b * NCH + ch) * T_FRAMES + t] = mag;
            }
        }
    }
}

extern "C" void kernel_launch(void* const* d_in, const int* in_sizes, int n_in,
                              void* d_out, int out_size, void* d_ws, size_t ws_size,
                              hipStream_t stream) {
    const float* x  = (const float*)d_in[0];
    const float* wt = (const float*)d_in[1];
    float* out = (float*)d_out;

    unsigned short* Xb = (unsigned short*)d_ws;                              // 16.04 MiB
    unsigned short* Wb = (unsigned short*)((char*)d_ws + (size_t)33554432);  // 2.25 MiB

    prep<<<XBLOCKS + WBLOCKS, 256, 0, stream>>>(x, wt, Xb, Wb);
    stft_gemm<<<dim3(2304), 256, 0, stream>>>(Xb, Wb, out);
}